// Round 8
// baseline (396.366 us; speedup 1.0000x reference)
//
#include <hip/hip_runtime.h>
#include <stdint.h>
#include <stddef.h>

typedef int v4i  __attribute__((ext_vector_type(4)));
typedef int v16i __attribute__((ext_vector_type(16)));

// Software q8: EXACT reference semantics (floor(log2), clamp[-6,8], half-even, sat 448).
__device__ __forceinline__ float q8f(float v) {
    float a = fabsf(v);
    int e = (int)(__float_as_uint(a) >> 23) - 127;
    e = e < -6 ? -6 : (e > 8 ? 8 : e);
    float step  = __uint_as_float((uint32_t)(e - 3 + 127) << 23);  // 2^(e-3)
    float rstep = __uint_as_float((uint32_t)(3 - e + 127) << 23);  // 2^(3-e)
    float q = fminf(rintf(a * rstep) * step, 448.0f);
    return v < 0.0f ? -q : q;
}
__device__ __forceinline__ int qm(float v) {  // q8 value * 512 (exact int)
    return (int)rintf(q8f(v) * 512.0f);
}

// integer round-half-even shift: RNE(a / 2^s), a >= 0, s >= 1
__device__ __forceinline__ uint32_t rne_sh(uint32_t a, int s) {
    uint32_t t = a >> s;
    uint32_t rem = a & ((1u << s) - 1u);
    uint32_t half = 1u << (s - 1);
    t += (rem > half) || (rem == half && (t & 1u));
    return t;
}

// Round-8 quant: EVERYTHING is packed into MFMA fragment order
//   addr(r,g,b) = ((r>>5)*(K/16) + g)*512 + (r&31)*16 + b
// x -> hi/lo planes (as round 7, coalesced 16B stores). NEW: w1/w2 are packed
// the same way (single i8 plane) so the GEMM loads B directly from global --
// the MFMA B-operand layout is symmetric to A (lane&31 = n-col, lane>>5 =
// k-half), eliminating LDS staging and all K-loop barriers in the GEMM.
// Thread mapping everywhere: lane owns (row, granule) = 16 consecutive k
// floats (4x float4 reads, full 64B line) -> ONE 16B packed store; a wave
// writes 1KB contiguous.
//   blocks [0,2048):    x  (256 rowgroups x 64 granules, 8 blk/rg)
//   blocks [2048,3072): w1 (128 rg x 64 g, 8 blk/rg)    K=1024
//   blocks [3072,4096): w2 (32 rg x 256 g, 32 blk/rg)   K=4096
__global__ __launch_bounds__(256) void quant_all_kernel(
    const float* __restrict__ x,  uint8_t* __restrict__ xh, uint8_t* __restrict__ xl,
    const float* __restrict__ w1, uint8_t* __restrict__ w1p,
    const float* __restrict__ w2, uint8_t* __restrict__ w2p) {
    const int blk = blockIdx.x;
    const int tid = threadIdx.x;
    const int wave = tid >> 6, lane = tid & 63;
    const int gsub = wave * 2 + (lane >> 5);   // 0..7: granule sub-index
    const int rr = lane & 31;                  // row within 32-row group
    if (blk < 2048) {
        const int rg = blk >> 3;
        const int g  = ((blk & 7) << 3) + gsub;
        const float* px = x + (size_t)(rg * 32 + rr) * 1024 + g * 16;
        v4i hv, lv;
#pragma unroll
        for (int q = 0; q < 4; ++q) {
            float4 v = ((const float4*)px)[q];
            int m0 = qm(v.x), m1 = qm(v.y), m2 = qm(v.z), m3 = qm(v.w);
            hv[q] = (int)(((uint32_t)((m0 >> 5) & 0xff)) | ((uint32_t)((m1 >> 5) & 0xff) << 8) |
                          ((uint32_t)((m2 >> 5) & 0xff) << 16) | ((uint32_t)((m3 >> 5) & 0xff) << 24));
            lv[q] = (int)(((uint32_t)(m0 & 31)) | ((uint32_t)(m1 & 31) << 8) |
                          ((uint32_t)(m2 & 31) << 16) | ((uint32_t)(m3 & 31) << 24));
        }
        const size_t pa = ((size_t)rg * 64 + g) * 512 + (size_t)rr * 16;
        *(v4i*)(xh + pa) = hv;
        *(v4i*)(xl + pa) = lv;
    } else if (blk < 3072) {
        const int j  = blk - 2048;
        const int rg = j >> 3;
        const int g  = ((j & 7) << 3) + gsub;
        const float* pw = w1 + (size_t)(rg * 32 + rr) * 1024 + g * 16;
        v4i bv;
#pragma unroll
        for (int q = 0; q < 4; ++q) {
            float4 v = ((const float4*)pw)[q];
            bv[q] = (int)(((uint32_t)(qm(v.x) & 0xff)) | ((uint32_t)(qm(v.y) & 0xff) << 8) |
                          ((uint32_t)(qm(v.z) & 0xff) << 16) | ((uint32_t)(qm(v.w) & 0xff) << 24));
        }
        *(v4i*)(w1p + ((size_t)rg * 64 + g) * 512 + (size_t)rr * 16) = bv;
    } else {
        const int j  = blk - 3072;
        const int rg = j >> 5;
        const int g  = ((j & 31) << 3) + gsub;
        const float* pw = w2 + (size_t)(rg * 32 + rr) * 4096 + g * 16;
        v4i bv;
#pragma unroll
        for (int q = 0; q < 4; ++q) {
            float4 v = ((const float4*)pw)[q];
            bv[q] = (int)(((uint32_t)(qm(v.x) & 0xff)) | ((uint32_t)(qm(v.y) & 0xff) << 8) |
                          ((uint32_t)(qm(v.z) & 0xff) << 16) | ((uint32_t)(qm(v.w) & 0xff) << 24));
        }
        *(v4i*)(w2p + ((size_t)rg * 256 + g) * 512 + (size_t)rr * 16) = bv;
    }
}

// C = (32*Ah + Al) * B^T * 2^-18, exact i32 via mfma_i32_32x32x32_i8.
// Round-8: ZERO LDS, ZERO staging. A and B are both packed fragment-order in
// global; per t-step each wave loads 2 A pairs (own rows, lane-linear 1KB) and
// 4 B tiles (shared across the block's 4 waves -> L1-filtered). vmcnt waits
// are all short-cover: b consumed 1 t after issue (~293 cyc cover, L1/L2 hit);
// A double-buffered per 4-t group (>=586 cyc cover; fc1 A L3-resident via
// re-reads, fc2 A L3-resident having just been written by fc1). One raw
// s_barrier per group bounds wave drift to the L1 B-window (no data crosses
// it; purely a rendezvous).
// 256 thr = 4 waves, block tile 128x128, wave tile 32x128.
//
// 1-D grid, XCD swizzle (bijective for 2048/512 blocks):
//   bm = (bid&7)*8 + (bid>>3)&7,  bn = (bid>>9)*8 + (bid>>6)&7
//
// EPI=0: q8+ReLU -> hi/lo planes written PACKED (K=N for next layer). EPI=1: fp32 row-major.
template <int EPI>
__global__ __launch_bounds__(256, 2) void gemm_i8_big(
    const uint8_t* __restrict__ Ah, const uint8_t* __restrict__ Al,
    const uint8_t* __restrict__ Bp,
    void* __restrict__ Ch, void* __restrict__ Cl,
    int M, int N, int K) {
    const int tid  = threadIdx.x;
    const int lane = tid & 63;
    const int wave = tid >> 6;     // 4 waves = 4 row strips
    const int col  = lane & 31;
    const int kh   = lane >> 5;

    const int bid = blockIdx.x;
    const int bm  = ((bid & 7) << 3) | ((bid >> 3) & 7);
    const int bn  = (((bid >> 9) << 3) | ((bid >> 6) & 7));

    v16i acc[2][4];
#pragma unroll
    for (int p = 0; p < 2; ++p)
#pragma unroll
        for (int j = 0; j < 4; ++j) acc[p][j] = (v16i)0;

    // packed A: row-block (bm*4 + wave); packed B: n-blocks bn*4 .. bn*4+3
    const size_t gstride = (size_t)(K >> 4) * 512;     // bytes per 32-row block
    const uint8_t* pAh = Ah + (size_t)(bm * 4 + wave) * gstride + lane * 16;
    const uint8_t* pAl = Al + (size_t)(bm * 4 + wave) * gstride + lane * 16;
    const uint8_t* pB  = Bp + (size_t)(bn * 4) * gstride + lane * 16;

    const int NT = K >> 5;   // t-steps (32 fc1 / 128 fc2)
    const int NG = NT >> 2;  // groups of 4 t-steps

    v4i ab[8], abn[8], bc[4], bn_[4];
    // prologue: A for group 0, B for t=0
#pragma unroll
    for (int u = 0; u < 4; ++u) {
        ab[2 * u]     = *(const v4i*)(pAh + u * 1024);
        ab[2 * u + 1] = *(const v4i*)(pAl + u * 1024);
    }
#pragma unroll
    for (int j = 0; j < 4; ++j) bc[j] = *(const v4i*)(pB + j * gstride);

    for (int g = 0; g < NG; ++g) {
        __builtin_amdgcn_s_barrier();   // rendezvous only: bound intra-block drift
        const int gn = (g + 1 < NG) ? (g + 1) : g;   // clamped (last reload redundant)
        const uint8_t* pAhn = pAh + (size_t)gn * 4096;
        const uint8_t* pAln = pAl + (size_t)gn * 4096;
#pragma unroll
        for (int u = 0; u < 4; ++u) {
            const int t  = g * 4 + u;
            const int tn = (t + 1 < NT) ? (t + 1) : t;
            // B prefetch for t+1 (issued first: its consume-wait next u has
            // ~1 t cover and only forces retirement of older, covered loads)
#pragma unroll
            for (int j = 0; j < 4; ++j)
                bn_[j] = *(const v4i*)(pB + j * gstride + (size_t)tn * 1024);
            // A pair for next group's u-th t-step (behind this u's B in FIFO)
            abn[2 * u]     = *(const v4i*)(pAhn + u * 1024);
            abn[2 * u + 1] = *(const v4i*)(pAln + u * 1024);
#pragma unroll
            for (int j = 0; j < 4; ++j) {
                acc[0][j] = __builtin_amdgcn_mfma_i32_32x32x32_i8(ab[2 * u],     bc[j], acc[0][j], 0, 0, 0);
                acc[1][j] = __builtin_amdgcn_mfma_i32_32x32x32_i8(ab[2 * u + 1], bc[j], acc[1][j], 0, 0, 0);
            }
#pragma unroll
            for (int j = 0; j < 4; ++j) bc[j] = bn_[j];
        }
#pragma unroll
        for (int r = 0; r < 8; ++r) ab[r] = abn[r];
    }

    // C/D layout (32x32): col = lane&31, row = (reg&3) + 8*(reg>>2) + 4*(lane>>5)
    const int Gn = N >> 4;  // granules per output row (packed dest, EPI=0)
    const int rb = bm * 4 + wave;
#pragma unroll
    for (int j = 0; j < 4; ++j) {
        const int colk = bn * 128 + j * 32 + col;
#pragma unroll
        for (int reg = 0; reg < 16; ++reg) {
            int mt = acc[0][j][reg] * 32 + acc[1][j][reg];  // exact, |mt| < 2^24
            const int rw = 4 * kh + (reg & 3) + 8 * (reg >> 2);  // row within 32
            if (EPI == 0) {
                uint8_t hb = 0, lb = 0;
                if (mt > 0) {
                    int s = 28 - __builtin_clz((uint32_t)mt);
                    if (s < 9) s = 9;
                    int mh = (int)(rne_sh((uint32_t)mt, s) << (s - 9));
                    hb = (uint8_t)(mh >> 5);
                    lb = (uint8_t)(mh & 31);
                }
                size_t pa = ((size_t)rb * Gn + (colk >> 4)) * 512 + rw * 16 + (colk & 15);
                ((uint8_t*)Ch)[pa] = hb;
                ((uint8_t*)Cl)[pa] = lb;
            } else {
                uint32_t a = mt < 0 ? (uint32_t)(-mt) : (uint32_t)mt;
                float v = 0.0f;
                if (a) {
                    int s = 28 - __builtin_clz(a);
                    if (s < 9) s = 9;
                    v = (float)(rne_sh(a, s) << s) * 0x1p-18f;  // exact
                    if (mt < 0) v = -v;
                }
                ((float*)Ch)[(size_t)(rb * 32 + rw) * N + colk] = v;
            }
        }
    }
}

extern "C" void kernel_launch(void* const* d_in, const int* in_sizes, int n_in,
                              void* d_out, int out_size, void* d_ws, size_t ws_size,
                              hipStream_t stream) {
    const int Bsz = 8192, DIN = 1024, DH = 4096, DOUT = 1024;
    const float* x  = (const float*)d_in[0];
    const float* w1 = (const float*)d_in[1];
    const float* w2 = (const float*)d_in[2];
    float* out = (float*)d_out;

    uint8_t* ws  = (uint8_t*)d_ws;
    uint8_t* xh  = ws;                            //  8 MB (packed)
    uint8_t* xl  = xh  + (size_t)Bsz * DIN;       //  8 MB (packed)
    uint8_t* w1p = xl  + (size_t)Bsz * DIN;       //  4 MB (packed)
    uint8_t* w2p = w1p + (size_t)DH  * DIN;       //  4 MB (packed)
    uint8_t* hh  = w2p + (size_t)DOUT * DH;       // 32 MB (packed)
    uint8_t* hl  = hh  + (size_t)Bsz * DH;        // 32 MB (packed)

    // quant: x (2048) + w1 (1024) + w2 (1024) blocks, all fragment-packed
    quant_all_kernel<<<4096, 256, 0, stream>>>(x, xh, xl, w1, w1p, w2, w2p);

    // fc1: h = relu(q8(x8 @ w1q^T)) -> packed hi/lo  [8192,4096]
    gemm_i8_big<0><<<dim3(2048), 256, 0, stream>>>(xh, xl, w1p, (void*)hh, (void*)hl, Bsz, DH, DIN);

    // fc2: out = q8(h @ w2q^T)  [8192,1024] fp32
    gemm_i8_big<1><<<dim3(512), 256, 0, stream>>>(hh, hl, w2p, (void*)out, nullptr, Bsz, DOUT, DH);
}

// Round 9
// 276.532 us; speedup vs baseline: 1.4333x; 1.4333x over previous
//
#include <hip/hip_runtime.h>
#include <stdint.h>
#include <stddef.h>

typedef int v4i  __attribute__((ext_vector_type(4)));
typedef int v16i __attribute__((ext_vector_type(16)));

#define KCH  256                 // K-chunk per LDS buffer (16 granules of 16 B)
#define BUFB (128 * 256)         // 32 KB per buffer: [row][slot] 16B units
#define LDSB (2 * BUFB)          // 64 KB -> 2 blocks/CU

#define FENCE() asm volatile("" ::: "memory")

// async global->LDS, 16B per lane.
__device__ __forceinline__ void gl_lds16(const uint8_t* g, uint8_t* l) {
    __builtin_amdgcn_global_load_lds(
        (const __attribute__((address_space(1))) uint32_t*)g,
        (__attribute__((address_space(3))) uint32_t*)l,
        16, 0, 0);
}

// Software q8: EXACT reference semantics (floor(log2), clamp[-6,8], half-even, sat 448).
__device__ __forceinline__ float q8f(float v) {
    float a = fabsf(v);
    int e = (int)(__float_as_uint(a) >> 23) - 127;
    e = e < -6 ? -6 : (e > 8 ? 8 : e);
    float step  = __uint_as_float((uint32_t)(e - 3 + 127) << 23);  // 2^(e-3)
    float rstep = __uint_as_float((uint32_t)(3 - e + 127) << 23);  // 2^(3-e)
    float q = fminf(rintf(a * rstep) * step, 448.0f);
    return v < 0.0f ? -q : q;
}
__device__ __forceinline__ int qm(float v) {  // q8 value * 512 (exact int)
    return (int)rintf(q8f(v) * 512.0f);
}

// integer round-half-even shift: RNE(a / 2^s), a >= 0, s >= 1
__device__ __forceinline__ uint32_t rne_sh(uint32_t a, int s) {
    uint32_t t = a >> s;
    uint32_t rem = a & ((1u << s) - 1u);
    uint32_t half = 1u << (s - 1);
    t += (rem > half) || (rem == half && (t & 1u));
    return t;
}

// Round-7 quant (kept verbatim; measured ~15-20us). x packed fragment-order
// with coalesced 16B stores; w1/w2 row-major u32.
__global__ __launch_bounds__(256) void quant_all_kernel(
    const float* __restrict__ x,  uint8_t* __restrict__ xh, uint8_t* __restrict__ xl,
    const float* __restrict__ w1, uint32_t* __restrict__ w1m,
    const float* __restrict__ w2, uint32_t* __restrict__ w2m) {
    const int blk = blockIdx.x;
    const int tid = threadIdx.x;
    if (blk < 2048) {
        const int wave = tid >> 6, lane = tid & 63;
        const int rg = blk >> 3;                                // 32-row group, 0..255
        const int g  = ((blk & 7) << 3) + wave * 2 + (lane >> 5); // granule 0..63
        const int r  = rg * 32 + (lane & 31);
        const float* px = x + (size_t)r * 1024 + g * 16;
        v4i hv, lv;
#pragma unroll
        for (int q = 0; q < 4; ++q) {
            float4 v = ((const float4*)px)[q];
            int m0 = qm(v.x), m1 = qm(v.y), m2 = qm(v.z), m3 = qm(v.w);
            hv[q] = (int)(((uint32_t)((m0 >> 5) & 0xff)) | ((uint32_t)((m1 >> 5) & 0xff) << 8) |
                          ((uint32_t)((m2 >> 5) & 0xff) << 16) | ((uint32_t)((m3 >> 5) & 0xff) << 24));
            lv[q] = (int)(((uint32_t)(m0 & 31)) | ((uint32_t)(m1 & 31) << 8) |
                          ((uint32_t)(m2 & 31) << 16) | ((uint32_t)(m3 & 31) << 24));
        }
        const size_t pa = ((size_t)rg * 64 + g) * 512 + (size_t)(lane & 31) * 16;
        *(v4i*)(xh + pa) = hv;
        *(v4i*)(xl + pa) = lv;
    } else if (blk < 2048 + 4096) {
        int j = (blk - 2048) * 256 + tid;        // over DH*DIN/4 = 1M float4
        float4 v = ((const float4*)w1)[j];
        w1m[j] = ((uint32_t)(qm(v.x) & 0xff)) | ((uint32_t)(qm(v.y) & 0xff) << 8) |
                 ((uint32_t)(qm(v.z) & 0xff) << 16) | ((uint32_t)(qm(v.w) & 0xff) << 24);
    } else {
        int j = (blk - 6144) * 256 + tid;        // over DOUT*DH/4 = 1M float4
        float4 v = ((const float4*)w2)[j];
        w2m[j] = ((uint32_t)(qm(v.x) & 0xff)) | ((uint32_t)(qm(v.y) & 0xff) << 8) |
                 ((uint32_t)(qm(v.z) & 0xff) << 16) | ((uint32_t)(qm(v.w) & 0xff) << 24);
    }
}

// Stage one K-chunk of B (row-major) into LDS [row][slot], slot = g ^ (row&15).
// Per inst: 4 consecutive rows, 16 fully-used lines. 4 waves, 8 insts each.
__device__ __forceinline__ void stage_chunk(
    const uint8_t* __restrict__ Bm, uint8_t* dst,
    int bn, int K, int kc, int wave, int lane) {
    const int r0 = lane >> 4;
    const int sl = lane & 15;
#pragma unroll
    for (int s = 0; s < 8; ++s) {
        const int qd  = wave * 8 + s;
        const int row = qd * 4 + r0;
        const int g   = sl ^ (row & 15);
        gl_lds16(Bm + (size_t)(bn * 128 + row) * K + kc + g * 16,
                 dst + qd * 1024 + lane * 16);
    }
}

// C = (32*Ah + Al) * Bm^T * 2^-18, exact i32 via mfma_i32_32x32x32_i8.
// 256 thr = 4 waves, block tile 128x128, wave tile 32x128, 2 blocks/CU.
//
// Round-9 K-loop: COUNTED-VMCNT PHASE PIPELINE (anti-convoy).
// Diagnosis: per t-step per CU: MFMA 586 cyc + LDS 385 + global 400 ~= wall
// 1650 -> pipes run SEQUENTIALLY (chunk-level convoy at __syncthreads: all
// waves burst loads together, wait together, MFMA together). Schedule (per
// wave vmem FIFO per chunk c):
//   [stage(c+1) x8][A-h1(c) x8] t0-3 (consume A-h0(c), loaded mid-chunk c-1,
//   4-phase cover) [A-h0(c+1) x8] t4-7 (consume A-h1(c); its auto vmcnt-wait
//   retires stage(c+1) as side effect, 4-phase cover).
// Raw s_barrier = rendezvous only: each wave's stage(c) provably retired by
// its A-h1(c-1) consume-wait at t4 of chunk c-1 (A-h1 issued after stage(c)
// in FIFO); cross-wave visibility via the barrier. No vmcnt(0) anywhere.
// LDS WAR safe: stage(c+1) targets buf^1 whose readers (chunk c-1) completed
// before the top-of-c barrier. T5: setprio(1) around each MFMA cluster
// (role diversity from the CU's 2 independent blocks).
//
// 1-D grid, XCD swizzle (bijective for 2048/512 blocks):
//   bm = (bid&7)*8 + (bid>>3)&7,  bn = (bid>>9)*8 + (bid>>6)&7
//
// EPI=0: q8+ReLU -> hi/lo planes written PACKED (K=N for next layer). EPI=1: fp32 row-major.
template <int EPI>
__global__ __launch_bounds__(256, 2) void gemm_i8_big(
    const uint8_t* __restrict__ Ah, const uint8_t* __restrict__ Al,
    const uint8_t* __restrict__ Bm,
    void* __restrict__ Ch, void* __restrict__ Cl,
    int M, int N, int K) {
    extern __shared__ uint8_t sB[];  // 2 x BUFB

    const int tid  = threadIdx.x;
    const int lane = tid & 63;
    const int wave = tid >> 6;     // 4 waves = 4 row strips
    const int col  = lane & 31;
    const int kh   = lane >> 5;
    const int xm   = col & 15;

    const int bid = blockIdx.x;
    const int bm  = ((bid & 7) << 3) | ((bid >> 3) & 7);
    const int bn  = (((bid >> 9) << 3) | ((bid >> 6) & 7));

    v16i acc[2][4];
#pragma unroll
    for (int p = 0; p < 2; ++p)
#pragma unroll
        for (int j = 0; j < 4; ++j) acc[p][j] = (v16i)0;

    // packed A: row-block (bm*4 + wave), sequential 1KB per t-step across all K
    const size_t abase = (size_t)(bm * 4 + wave) * (K >> 4) * 512 + lane * 16;
    const uint8_t* pAh = Ah + abase;
    const uint8_t* pAl = Al + abase;

    int rowoff[4];
#pragma unroll
    for (int j = 0; j < 4; ++j) rowoff[j] = (j * 32 + col) * 256;

    const int NC = K / KCH;    // 4 (fc1) / 16 (fc2)

    // ---- prologue: stage(0), A-h0(0); retire ONLY stage(0) (counted wait) ----
    stage_chunk(Bm, sB, bn, K, 0, wave, lane);
    FENCE();
    v4i a0[8], a1[8];
#pragma unroll
    for (int u = 0; u < 4; ++u) {
        a0[2 * u]     = *(const v4i*)(pAh + u * 1024);
        a0[2 * u + 1] = *(const v4i*)(pAl + u * 1024);
    }
    FENCE();
    asm volatile("s_waitcnt vmcnt(8)" ::: "memory");   // stage(0) landed; A-h0 in flight

    for (int c = 0; c < NC; ++c) {
        __builtin_amdgcn_s_barrier();   // rendezvous: buf(c) ready for all waves
        FENCE();
        const uint8_t* buf  = sB + (c & 1) * BUFB;
        const uint8_t* pAhc = pAh + (size_t)c * 8192;   // 8 t-steps x 1KB
        const uint8_t* pAlc = pAl + (size_t)c * 8192;

        // (1) stage(c+1) -> buf^1 (readers of buf^1 finished before the barrier)
        if (c + 1 < NC)
            stage_chunk(Bm, sB + ((c + 1) & 1) * BUFB, bn, K, (c + 1) * KCH, wave, lane);
        FENCE();
        // (2) A-h1(c): pairs for t4-7 (after stage in FIFO -> their consume-wait
        //     at t4 retires stage(c+1) with ~4 phases of cover)
#pragma unroll
        for (int u = 0; u < 4; ++u) {
            a1[2 * u]     = *(const v4i*)(pAhc + (4 + u) * 1024);
            a1[2 * u + 1] = *(const v4i*)(pAlc + (4 + u) * 1024);
        }
        FENCE();

        // (3) t0-3: consume A-h0(c) (loaded mid-chunk c-1 -> covered)
#pragma unroll
        for (int u = 0; u < 4; ++u) {
            const int slot = ((2 * u + kh) & 15) ^ xm;
            v4i b[4];
#pragma unroll
            for (int j = 0; j < 4; ++j)
                b[j] = *(const v4i*)(buf + rowoff[j] + slot * 16);
            __builtin_amdgcn_s_setprio(1);
#pragma unroll
            for (int j = 0; j < 4; ++j) {
                acc[0][j] = __builtin_amdgcn_mfma_i32_32x32x32_i8(a0[2 * u],     b[j], acc[0][j], 0, 0, 0);
                acc[1][j] = __builtin_amdgcn_mfma_i32_32x32x32_i8(a0[2 * u + 1], b[j], acc[1][j], 0, 0, 0);
            }
            __builtin_amdgcn_s_setprio(0);
        }
        FENCE();

        // (4) A-h0(c+1): pairs for t0-3 of next chunk (4-phase cover to next t0)
        if (c + 1 < NC) {
#pragma unroll
            for (int u = 0; u < 4; ++u) {
                a0[2 * u]     = *(const v4i*)(pAhc + 8192 + u * 1024);
                a0[2 * u + 1] = *(const v4i*)(pAlc + 8192 + u * 1024);
            }
        }
        FENCE();

        // (5) t4-7: consume A-h1(c)
#pragma unroll
        for (int u = 0; u < 4; ++u) {
            const int slot = ((2 * (4 + u) + kh) & 15) ^ xm;
            v4i b[4];
#pragma unroll
            for (int j = 0; j < 4; ++j)
                b[j] = *(const v4i*)(buf + rowoff[j] + slot * 16);
            __builtin_amdgcn_s_setprio(1);
#pragma unroll
            for (int j = 0; j < 4; ++j) {
                acc[0][j] = __builtin_amdgcn_mfma_i32_32x32x32_i8(a1[2 * u],     b[j], acc[0][j], 0, 0, 0);
                acc[1][j] = __builtin_amdgcn_mfma_i32_32x32x32_i8(a1[2 * u + 1], b[j], acc[1][j], 0, 0, 0);
            }
            __builtin_amdgcn_s_setprio(0);
        }
        FENCE();
    }

    // C/D layout (32x32): col = lane&31, row = (reg&3) + 8*(reg>>2) + 4*(lane>>5)
    const int Gn = N >> 4;  // granules per output row (packed dest, EPI=0)
    const int rb = bm * 4 + wave;
#pragma unroll
    for (int j = 0; j < 4; ++j) {
        const int colk = bn * 128 + j * 32 + col;
#pragma unroll
        for (int reg = 0; reg < 16; ++reg) {
            int mt = acc[0][j][reg] * 32 + acc[1][j][reg];  // exact, |mt| < 2^24
            const int rw = 4 * kh + (reg & 3) + 8 * (reg >> 2);  // row within 32
            if (EPI == 0) {
                uint8_t hb = 0, lb = 0;
                if (mt > 0) {
                    int s = 28 - __builtin_clz((uint32_t)mt);
                    if (s < 9) s = 9;
                    int mh = (int)(rne_sh((uint32_t)mt, s) << (s - 9));
                    hb = (uint8_t)(mh >> 5);
                    lb = (uint8_t)(mh & 31);
                }
                size_t pa = ((size_t)rb * Gn + (colk >> 4)) * 512 + rw * 16 + (colk & 15);
                ((uint8_t*)Ch)[pa] = hb;
                ((uint8_t*)Cl)[pa] = lb;
            } else {
                uint32_t a = mt < 0 ? (uint32_t)(-mt) : (uint32_t)mt;
                float v = 0.0f;
                if (a) {
                    int s = 28 - __builtin_clz(a);
                    if (s < 9) s = 9;
                    v = (float)(rne_sh(a, s) << s) * 0x1p-18f;  // exact
                    if (mt < 0) v = -v;
                }
                ((float*)Ch)[(size_t)(rb * 32 + rw) * N + colk] = v;
            }
        }
    }
}

extern "C" void kernel_launch(void* const* d_in, const int* in_sizes, int n_in,
                              void* d_out, int out_size, void* d_ws, size_t ws_size,
                              hipStream_t stream) {
    const int Bsz = 8192, DIN = 1024, DH = 4096, DOUT = 1024;
    const float* x  = (const float*)d_in[0];
    const float* w1 = (const float*)d_in[1];
    const float* w2 = (const float*)d_in[2];
    float* out = (float*)d_out;

    uint8_t* ws  = (uint8_t*)d_ws;
    uint8_t* xh  = ws;                            //  8 MB (packed)
    uint8_t* xl  = xh  + (size_t)Bsz * DIN;       //  8 MB (packed)
    uint8_t* w1m = xl  + (size_t)Bsz * DIN;       //  4 MB
    uint8_t* w2m = w1m + (size_t)DH  * DIN;       //  4 MB
    uint8_t* hh  = w2m + (size_t)DOUT * DH;       // 32 MB (packed)
    uint8_t* hl  = hh  + (size_t)Bsz * DH;        // 32 MB (packed)

    static bool attr_done = false;
    if (!attr_done) {
        hipFuncSetAttribute((const void*)gemm_i8_big<0>,
                            hipFuncAttributeMaxDynamicSharedMemorySize, LDSB);
        hipFuncSetAttribute((const void*)gemm_i8_big<1>,
                            hipFuncAttributeMaxDynamicSharedMemorySize, LDSB);
        attr_done = true;
    }

    // quant: 2048 blocks for x (coalesced packed writes) + 4096 (w1) + 4096 (w2)
    quant_all_kernel<<<10240, 256, 0, stream>>>(
        x, xh, xl, w1, (uint32_t*)w1m, w2, (uint32_t*)w2m);

    // fc1: h = relu(q8(x8 @ w1q^T)) -> packed hi/lo  [8192,4096]
    gemm_i8_big<0><<<dim3(2048), 256, LDSB, stream>>>(xh, xl, w1m, (void*)hh, (void*)hl, Bsz, DH, DIN);

    // fc2: out = q8(h @ w2q^T)  [8192,1024] fp32
    gemm_i8_big<1><<<dim3(512), 256, LDSB, stream>>>(hh, hl, w2m, (void*)out, nullptr, Bsz, DOUT, DH);
}

// Round 11
// 244.616 us; speedup vs baseline: 1.6204x; 1.1305x over previous
//
#include <hip/hip_runtime.h>
#include <stdint.h>
#include <stddef.h>

typedef int v4i  __attribute__((ext_vector_type(4)));
typedef int v16i __attribute__((ext_vector_type(16)));

#define KCH  256                 // K-chunk per LDS buffer (16 granules of 16 B)
#define BUFB (128 * 256)         // 32 KB per buffer: [row][slot] 16B units
#define LDSB (2 * BUFB)          // 64 KB -> 2 blocks/CU

#define FENCE() asm volatile("" ::: "memory")

// async global->LDS, 16B per lane.
__device__ __forceinline__ void gl_lds16(const uint8_t* g, uint8_t* l) {
    __builtin_amdgcn_global_load_lds(
        (const __attribute__((address_space(1))) uint32_t*)g,
        (__attribute__((address_space(3))) uint32_t*)l,
        16, 0, 0);
}

// Software q8: EXACT reference semantics (floor(log2), clamp[-6,8], half-even, sat 448).
__device__ __forceinline__ float q8f(float v) {
    float a = fabsf(v);
    int e = (int)(__float_as_uint(a) >> 23) - 127;
    e = e < -6 ? -6 : (e > 8 ? 8 : e);
    float step  = __uint_as_float((uint32_t)(e - 3 + 127) << 23);  // 2^(e-3)
    float rstep = __uint_as_float((uint32_t)(3 - e + 127) << 23);  // 2^(3-e)
    float q = fminf(rintf(a * rstep) * step, 448.0f);
    return v < 0.0f ? -q : q;
}
__device__ __forceinline__ int qm(float v) {  // q8 value * 512 (exact int)
    return (int)rintf(q8f(v) * 512.0f);
}

// integer round-half-even shift: RNE(a / 2^s), a >= 0, s >= 1
__device__ __forceinline__ uint32_t rne_sh(uint32_t a, int s) {
    uint32_t t = a >> s;
    uint32_t rem = a & ((1u << s) - 1u);
    uint32_t half = 1u << (s - 1);
    t += (rem > half) || (rem == half && (t & 1u));
    return t;
}

// Round-7 quant (kept verbatim). x packed fragment-order with coalesced 16B
// stores; w1/w2 row-major u32.
__global__ __launch_bounds__(256) void quant_all_kernel(
    const float* __restrict__ x,  uint8_t* __restrict__ xh, uint8_t* __restrict__ xl,
    const float* __restrict__ w1, uint32_t* __restrict__ w1m,
    const float* __restrict__ w2, uint32_t* __restrict__ w2m) {
    const int blk = blockIdx.x;
    const int tid = threadIdx.x;
    if (blk < 2048) {
        const int wave = tid >> 6, lane = tid & 63;
        const int rg = blk >> 3;                                // 32-row group, 0..255
        const int g  = ((blk & 7) << 3) + wave * 2 + (lane >> 5); // granule 0..63
        const int r  = rg * 32 + (lane & 31);
        const float* px = x + (size_t)r * 1024 + g * 16;
        v4i hv, lv;
#pragma unroll
        for (int q = 0; q < 4; ++q) {
            float4 v = ((const float4*)px)[q];
            int m0 = qm(v.x), m1 = qm(v.y), m2 = qm(v.z), m3 = qm(v.w);
            hv[q] = (int)(((uint32_t)((m0 >> 5) & 0xff)) | ((uint32_t)((m1 >> 5) & 0xff) << 8) |
                          ((uint32_t)((m2 >> 5) & 0xff) << 16) | ((uint32_t)((m3 >> 5) & 0xff) << 24));
            lv[q] = (int)(((uint32_t)(m0 & 31)) | ((uint32_t)(m1 & 31) << 8) |
                          ((uint32_t)(m2 & 31) << 16) | ((uint32_t)(m3 & 31) << 24));
        }
        const size_t pa = ((size_t)rg * 64 + g) * 512 + (size_t)(lane & 31) * 16;
        *(v4i*)(xh + pa) = hv;
        *(v4i*)(xl + pa) = lv;
    } else if (blk < 2048 + 4096) {
        int j = (blk - 2048) * 256 + tid;        // over DH*DIN/4 = 1M float4
        float4 v = ((const float4*)w1)[j];
        w1m[j] = ((uint32_t)(qm(v.x) & 0xff)) | ((uint32_t)(qm(v.y) & 0xff) << 8) |
                 ((uint32_t)(qm(v.z) & 0xff) << 16) | ((uint32_t)(qm(v.w) & 0xff) << 24);
    } else {
        int j = (blk - 6144) * 256 + tid;        // over DOUT*DH/4 = 1M float4
        float4 v = ((const float4*)w2)[j];
        w2m[j] = ((uint32_t)(qm(v.x) & 0xff)) | ((uint32_t)(qm(v.y) & 0xff) << 8) |
                 ((uint32_t)(qm(v.z) & 0xff) << 16) | ((uint32_t)(qm(v.w) & 0xff) << 24);
    }
}

// Full-chunk stage (prologue only): [row][slot], slot = g ^ (row&15).
__device__ __forceinline__ void stage_chunk(
    const uint8_t* __restrict__ Bm, uint8_t* dst,
    int bn, int K, int kc, int wave, int lane) {
    const int r0 = lane >> 4;
    const int sl = lane & 15;
#pragma unroll
    for (int s = 0; s < 8; ++s) {
        const int qd  = wave * 8 + s;
        const int row = qd * 4 + r0;
        const int g   = sl ^ (row & 15);
        gl_lds16(Bm + (size_t)(bn * 128 + row) * K + kc + g * 16,
                 dst + qd * 1024 + lane * 16);
    }
}

// Two of the 8 per-wave staging gl_lds (s = 2p, 2p+1) — spread across phases.
__device__ __forceinline__ void stage_pair(
    const uint8_t* __restrict__ Bm, uint8_t* dst,
    int bn, int K, int kc, int wave, int lane, int p) {
    const int r0 = lane >> 4;
    const int sl = lane & 15;
#pragma unroll
    for (int s = 2 * p; s < 2 * p + 2; ++s) {
        const int qd  = wave * 8 + s;
        const int row = qd * 4 + r0;
        const int g   = sl ^ (row & 15);
        gl_lds16(Bm + (size_t)(bn * 128 + row) * K + kc + g * 16,
                 dst + qd * 1024 + lane * 16);
    }
}

// C = (32*Ah + Al) * Bm^T * 2^-18, exact i32 via mfma_i32_32x32x32_i8.
// 256 thr = 4 waves, block tile 128x128, wave tile 32x128, 2 blocks/CU.
//
// Round-11 = round-10 anti-convoy counted-vmcnt phases + RACE FIX.
// r10's tripwire = WAR race: a wave could reach the raw s_barrier with its
// last-phase ds_reads still queued in the DS unit (their MFMA consumers are
// register-only and can be sunk past inline-asm by the compiler, rule #18);
// another wave's post-barrier gl_lds DMA then overwrote the target buffer.
// Fix: (1) s_waitcnt lgkmcnt(0) before every s_barrier (all own LDS reads
// processed before signaling; ~free, data-deps drain them anyway);
// (2) sched_barrier(0) after each inline waitcnt (pins MFMA movement).
// Counted-vmcnt structure unchanged: per chunk 4 phases x 2 t-steps, per-wave
// vmem FIFO [stage-pair(c+1) x2][A-pair x2 next phase] -> ds_read+MFMA on A
// loaded last phase; one vmcnt(4) per chunk (retires own last stage pair,
// keeps 4 A loads in flight across the barrier). NO vmcnt(0) anywhere.
// Registers: acc 128 AGPR + aC/aN 32 + b 16 + addr ~25 ~= 200 of 256.
//
// 1-D grid, XCD swizzle (bijective for 2048/512 blocks):
//   bm = (bid&7)*8 + (bid>>3)&7,  bn = (bid>>9)*8 + (bid>>6)&7
//
// EPI=0: q8+ReLU -> hi/lo planes written PACKED (K=N for next layer). EPI=1: fp32 row-major.
template <int EPI>
__global__ __launch_bounds__(256, 2) void gemm_i8_big(
    const uint8_t* __restrict__ Ah, const uint8_t* __restrict__ Al,
    const uint8_t* __restrict__ Bm,
    void* __restrict__ Ch, void* __restrict__ Cl,
    int M, int N, int K) {
    extern __shared__ uint8_t sB[];  // 2 x BUFB

    const int tid  = threadIdx.x;
    const int lane = tid & 63;
    const int wave = tid >> 6;     // 4 waves = 4 row strips
    const int col  = lane & 31;
    const int kh   = lane >> 5;
    const int xm   = col & 15;

    const int bid = blockIdx.x;
    const int bm  = ((bid & 7) << 3) | ((bid >> 3) & 7);
    const int bn  = (((bid >> 9) << 3) | ((bid >> 6) & 7));

    v16i acc[2][4];
#pragma unroll
    for (int p = 0; p < 2; ++p)
#pragma unroll
        for (int j = 0; j < 4; ++j) acc[p][j] = (v16i)0;

    // packed A: row-block (bm*4 + wave), sequential 1KB per t-step across all K
    const size_t abase = (size_t)(bm * 4 + wave) * (K >> 4) * 512 + lane * 16;
    const uint8_t* pAh = Ah + abase;
    const uint8_t* pAl = Al + abase;

    int rowoff[4];
#pragma unroll
    for (int j = 0; j < 4; ++j) rowoff[j] = (j * 32 + col) * 256;

    const int NC = K / KCH;    // 4 (fc1) / 16 (fc2)

    // ---- prologue: stage(0) x8, A pairs for t0,t1; counted wait (stage landed,
    //      A stays in flight) ----
    stage_chunk(Bm, sB, bn, K, 0, wave, lane);
    FENCE();
    v4i aC0 = *(const v4i*)(pAh);
    v4i aC1 = *(const v4i*)(pAl);
    v4i aC2 = *(const v4i*)(pAh + 1024);
    v4i aC3 = *(const v4i*)(pAl + 1024);
    FENCE();
    asm volatile("s_waitcnt vmcnt(4)" ::: "memory");
    __builtin_amdgcn_sched_barrier(0);

    for (int c = 0; c < NC; ++c) {
        // RACE FIX: own LDS reads fully processed before signaling the barrier
        asm volatile("s_waitcnt lgkmcnt(0)" ::: "memory");
        __builtin_amdgcn_sched_barrier(0);
        __builtin_amdgcn_s_barrier();   // rendezvous: buf(c) staged for all waves
        FENCE();
        const uint8_t* buf  = sB + (c & 1) * BUFB;
        uint8_t*       nbuf = sB + ((c + 1) & 1) * BUFB;
        const bool  more    = (c + 1 < NC);
        const int   nkc     = (c + 1) * KCH;
        const uint8_t* pAhc = pAh + (size_t)c * 8192;   // 8 t-steps x 1KB
        const uint8_t* pAlc = pAl + (size_t)c * 8192;
        const size_t next_off = more ? 8192 : 0;        // clamp last chunk

#pragma unroll
        for (int p = 0; p < 4; ++p) {
            // (a) 2 staging gl_lds for chunk c+1 (FIRST in FIFO: later A-consume
            //     retires them with ~1 phase of cover; never waited directly)
            if (more) stage_pair(Bm, nbuf, bn, K, nkc, wave, lane, p);
            FENCE();
            // (b) A pairs for the NEXT phase (p=3 -> t0,t1 of chunk c+1)
            const size_t tb = (p == 3) ? next_off : (size_t)(2 * p + 2) * 1024;
            v4i aN0 = *(const v4i*)(pAhc + tb);
            v4i aN1 = *(const v4i*)(pAlc + tb);
            v4i aN2 = *(const v4i*)(pAhc + tb + 1024);
            v4i aN3 = *(const v4i*)(pAlc + tb + 1024);
            FENCE();
            // (c) two t-steps consuming aC (loaded last phase -> counted wait)
#pragma unroll
            for (int e = 0; e < 2; ++e) {
                const int t = 2 * p + e;
                const int slot = ((2 * t + kh) & 15) ^ xm;
                v4i b[4];
#pragma unroll
                for (int j = 0; j < 4; ++j)
                    b[j] = *(const v4i*)(buf + rowoff[j] + slot * 16);
                __builtin_amdgcn_s_setprio(1);
                if (e == 0) {
#pragma unroll
                    for (int j = 0; j < 4; ++j) {
                        acc[0][j] = __builtin_amdgcn_mfma_i32_32x32x32_i8(aC0, b[j], acc[0][j], 0, 0, 0);
                        acc[1][j] = __builtin_amdgcn_mfma_i32_32x32x32_i8(aC1, b[j], acc[1][j], 0, 0, 0);
                    }
                } else {
#pragma unroll
                    for (int j = 0; j < 4; ++j) {
                        acc[0][j] = __builtin_amdgcn_mfma_i32_32x32x32_i8(aC2, b[j], acc[0][j], 0, 0, 0);
                        acc[1][j] = __builtin_amdgcn_mfma_i32_32x32x32_i8(aC3, b[j], acc[1][j], 0, 0, 0);
                    }
                }
                __builtin_amdgcn_s_setprio(0);
            }
            FENCE();
            aC0 = aN0; aC1 = aN1; aC2 = aN2; aC3 = aN3;
        }
        // own stage(c+1) pairs landed (last pair: ~1 phase cover); the 4
        // in-flight A loads for chunk c+1 stay outstanding across the barrier
        asm volatile("s_waitcnt vmcnt(4)" ::: "memory");
        __builtin_amdgcn_sched_barrier(0);
    }

    // C/D layout (32x32): col = lane&31, row = (reg&3) + 8*(reg>>2) + 4*(lane>>5)
    const int Gn = N >> 4;  // granules per output row (packed dest, EPI=0)
    const int rb = bm * 4 + wave;
#pragma unroll
    for (int j = 0; j < 4; ++j) {
        const int colk = bn * 128 + j * 32 + col;
#pragma unroll
        for (int reg = 0; reg < 16; ++reg) {
            int mt = acc[0][j][reg] * 32 + acc[1][j][reg];  // exact, |mt| < 2^24
            const int rw = 4 * kh + (reg & 3) + 8 * (reg >> 2);  // row within 32
            if (EPI == 0) {
                uint8_t hb = 0, lb = 0;
                if (mt > 0) {
                    int s = 28 - __builtin_clz((uint32_t)mt);
                    if (s < 9) s = 9;
                    int mh = (int)(rne_sh((uint32_t)mt, s) << (s - 9));
                    hb = (uint8_t)(mh >> 5);
                    lb = (uint8_t)(mh & 31);
                }
                size_t pa = ((size_t)rb * Gn + (colk >> 4)) * 512 + rw * 16 + (colk & 15);
                ((uint8_t*)Ch)[pa] = hb;
                ((uint8_t*)Cl)[pa] = lb;
            } else {
                uint32_t a = mt < 0 ? (uint32_t)(-mt) : (uint32_t)mt;
                float v = 0.0f;
                if (a) {
                    int s = 28 - __builtin_clz(a);
                    if (s < 9) s = 9;
                    v = (float)(rne_sh(a, s) << s) * 0x1p-18f;  // exact
                    if (mt < 0) v = -v;
                }
                ((float*)Ch)[(size_t)(rb * 32 + rw) * N + colk] = v;
            }
        }
    }
}

extern "C" void kernel_launch(void* const* d_in, const int* in_sizes, int n_in,
                              void* d_out, int out_size, void* d_ws, size_t ws_size,
                              hipStream_t stream) {
    const int Bsz = 8192, DIN = 1024, DH = 4096, DOUT = 1024;
    const float* x  = (const float*)d_in[0];
    const float* w1 = (const float*)d_in[1];
    const float* w2 = (const float*)d_in[2];
    float* out = (float*)d_out;

    uint8_t* ws  = (uint8_t*)d_ws;
    uint8_t* xh  = ws;                            //  8 MB (packed)
    uint8_t* xl  = xh  + (size_t)Bsz * DIN;       //  8 MB (packed)
    uint8_t* w1m = xl  + (size_t)Bsz * DIN;       //  4 MB
    uint8_t* w2m = w1m + (size_t)DH  * DIN;       //  4 MB
    uint8_t* hh  = w2m + (size_t)DOUT * DH;       // 32 MB (packed)
    uint8_t* hl  = hh  + (size_t)Bsz * DH;        // 32 MB (packed)

    // unconditional (identical every call; no call-count branching)
    hipFuncSetAttribute((const void*)gemm_i8_big<0>,
                        hipFuncAttributeMaxDynamicSharedMemorySize, LDSB);
    hipFuncSetAttribute((const void*)gemm_i8_big<1>,
                        hipFuncAttributeMaxDynamicSharedMemorySize, LDSB);

    // quant: 2048 blocks for x (coalesced packed writes) + 4096 (w1) + 4096 (w2)
    quant_all_kernel<<<10240, 256, 0, stream>>>(
        x, xh, xl, w1, (uint32_t*)w1m, w2, (uint32_t*)w2m);

    // fc1: h = relu(q8(x8 @ w1q^T)) -> packed hi/lo  [8192,4096]
    gemm_i8_big<0><<<dim3(2048), 256, LDSB, stream>>>(xh, xl, w1m, (void*)hh, (void*)hl, Bsz, DH, DIN);

    // fc2: out = q8(h @ w2q^T)  [8192,1024] fp32
    gemm_i8_big<1><<<dim3(512), 256, LDSB, stream>>>(hh, hl, w2m, (void*)out, nullptr, Bsz, DOUT, DH);
}